// Round 8
// baseline (316.816 us; speedup 1.0000x reference)
//
#include <hip/hip_runtime.h>
#include <cstdint>
#include <cstddef>

typedef _Float16 f16;
typedef _Float16 f16x4 __attribute__((ext_vector_type(4)));
typedef _Float16 f16x8 __attribute__((ext_vector_type(8)));
typedef float f32x4 __attribute__((ext_vector_type(4)));

#define MFMA32(a,b,c) __builtin_amdgcn_mfma_f32_16x16x32_f16((a),(b),(c),0,0,0)
#define MFMA16(a,b,c) __builtin_amdgcn_mfma_f32_16x16x16f16((a),(b),(c),0,0,0)

__device__ __forceinline__ float fexp2(float x) {
#if __has_builtin(__builtin_amdgcn_exp2f)
  return __builtin_amdgcn_exp2f(x);
#else
  return __expf(x * 0.69314718055994531f);
#endif
}

__device__ __forceinline__ void gload_lds16(const f16* g, f16* l) {
  __builtin_amdgcn_global_load_lds(
      (const __attribute__((address_space(1))) unsigned int*)g,
      (__attribute__((address_space(3))) unsigned int*)l, 16, 0, 0);
}

// ---------------- workspace layout (bytes) ----------------
static constexpr size_t OFF_TCPB = 0;                     // 3969*16*4 fp32 (base-2 domain)
static constexpr size_t OFF_BIAS = 262144;                // 16*1024*1024 f16  [h][m>>2][n][m&3]
static constexpr size_t OFF_XHI  = OFF_BIAS + 33554432;   // 8192*512 f16   (reused: po split1)
static constexpr size_t OFF_XLO  = OFF_XHI + 8388608;     //                (reused: ml0, ml1)
static constexpr size_t OFF_WHI  = OFF_XLO + 8388608;     // 1536*512 f16
static constexpr size_t OFF_WLO  = OFF_WHI + 1572864;     // (dead)
static constexpr size_t OFF_PW   = OFF_WLO + 1572864;     // 512*512 f16
static constexpr size_t OFF_QHI  = OFF_PW  + 524288;      // [B][H][N][32] f16 (pre-scaled q)
static constexpr size_t OFF_QLO  = OFF_QHI + 8388608;     // (dead)
static constexpr size_t OFF_KHI  = OFF_QLO + 8388608;
static constexpr size_t OFF_KLO  = OFF_KHI + 8388608;     // (reused: po split0)
static constexpr size_t OFF_VT   = OFF_KLO + 8388608;     // [B][H][32][N] f16
static constexpr size_t OFF_AO   = OFF_VT  + 8388608;     // [8192][512] f16

// ---------------- kernel 1: fp32 -> f16 (x gets hi+lo split; weights hi only) -------------
__global__ __launch_bounds__(256) void k_convert(
    const float* __restrict__ x, const float* __restrict__ qw, const float* __restrict__ pwf,
    f16* __restrict__ xhi, f16* __restrict__ xlo,
    f16* __restrict__ whi, f16* __restrict__ pw)
{
  int i = blockIdx.x * 256 + threadIdx.x;
  const float4* src; f16* dh; f16* dl; int j;
  if (i < 1048576)      { j = i;           src = (const float4*)x;   dh = xhi; dl = xlo; }
  else if (i < 1245184) { j = i - 1048576; src = (const float4*)qw;  dh = whi; dl = nullptr; }
  else                  { j = i - 1245184; src = (const float4*)pwf; dh = pw;  dl = nullptr; }
  float4 v = src[j];
  f16x4 h;
  h[0] = (f16)v.x; h[1] = (f16)v.y; h[2] = (f16)v.z; h[3] = (f16)v.w;
  ((f16x4*)dh)[j] = h;
  if (dl) {
    f16x4 l;
    l[0] = (f16)(v.x - (float)h[0]); l[1] = (f16)(v.y - (float)h[1]);
    l[2] = (f16)(v.z - (float)h[2]); l[3] = (f16)(v.w - (float)h[3]);
    ((f16x4*)dl)[j] = l;
  }
}

// ---------------- kernel 2: CPB MLP -> t[3969][16] fp32, scaled by log2e ----------------
__global__ __launch_bounds__(256) void k_cpb(
    const float* __restrict__ table, const float* __restrict__ w1, const float* __restrict__ b1,
    const float* __restrict__ w2, const float* __restrict__ b2, float* __restrict__ t_out)
{
  const int r = blockIdx.x * 4 + (threadIdx.x >> 6);
  const int lane = threadIdx.x & 63;
  if (r >= 3969) return;
  const float c0 = table[2*r], c1 = table[2*r+1];
  const int j0 = lane * 8;
  float h[8];
#pragma unroll
  for (int jj = 0; jj < 8; jj++) {
    int j = j0 + jj;
    float v = c0 * w1[2*j] + c1 * w1[2*j+1] + b1[j];
    h[jj] = v > 0.0f ? v : 0.0f;
  }
  float acc[16];
#pragma unroll
  for (int o = 0; o < 16; o++) {
    const float4* wp = (const float4*)(w2 + o*512 + j0);
    float4 a = wp[0], bb = wp[1];
    acc[o] = a.x*h[0] + a.y*h[1] + a.z*h[2] + a.w*h[3]
           + bb.x*h[4] + bb.y*h[5] + bb.z*h[6] + bb.w*h[7];
  }
#pragma unroll
  for (int o = 0; o < 16; o++) {
    float v = acc[o];
    for (int s = 1; s < 64; s <<= 1) v += __shfl_xor(v, s, 64);
    acc[o] = v;
  }
  if (lane == 0) {
#pragma unroll
    for (int o = 0; o < 16; o++)
      t_out[r*16 + o] = (acc[o] + b2[o]) * 1.4426950408889634f;
  }
}

// ---------------- kernel 3: bias gather, vectorized rows -> [h][m>>2][n][m&3] -------------
__global__ __launch_bounds__(256) void k_bias(
    const int* __restrict__ idx, const float* __restrict__ t_cpb, f16* __restrict__ bias_t)
{
  int g = blockIdx.x * 256 + threadIdx.x;   // 262144 = 256 m4 * 1024 n
  int n = g & 1023, m4 = g >> 10;
  int4 I = *(const int4*)(idx + (size_t)n*1024 + m4*4);
  int ids[4] = {I.x, I.y, I.z, I.w};
  const float4* T = (const float4*)t_cpb;
#pragma unroll
  for (int half = 0; half < 2; half++) {
    float4 R[4][2];
#pragma unroll
    for (int k = 0; k < 4; k++) {
      R[k][0] = T[ids[k]*4 + half*2];
      R[k][1] = T[ids[k]*4 + half*2 + 1];
    }
#pragma unroll
    for (int hh = 0; hh < 8; hh++) {
      int h = half*8 + hh;
      f16x4 o;
#pragma unroll
      for (int k = 0; k < 4; k++)
        o[k] = (f16)(((const float*)&R[k][hh >> 2])[hh & 3]);
      *(f16x4*)(bias_t + (((size_t)h*256 + m4)*1024 + n)*4) = o;
    }
  }
}

// ---------------- kernel 4: QKV GEMM (x split, w single-f16) + normalize epilogue ---------
__global__ __launch_bounds__(256) void k_qkv(
    const f16* __restrict__ xhi, const f16* __restrict__ xlo,
    const f16* __restrict__ whi,
    const float* __restrict__ qkvb, const float* __restrict__ temp, const float* __restrict__ qe,
    f16* __restrict__ qh_o, f16* __restrict__ kh_o, f16* __restrict__ vt_o)
{
  __shared__ __align__(16) f16 Ah[8][64][8];
  __shared__ __align__(16) f16 Al[8][64][8];
  __shared__ __align__(16) f16 Bh[8][64][8];
  const int tid = threadIdx.x, lane = tid & 63, w = tid >> 6;
  const int rsel = lane & 15, ksel = lane >> 4;
  const int bx = blockIdx.x & 63, by = blockIdx.x >> 6;
  const int m0 = bx << 7, n0 = by << 7;
  const bool SPLIT = (by < 8);

  const size_t aoff = (size_t)(m0 + w*32 + rsel)*512 + ksel*8;
  const size_t boff = (size_t)(n0 + w*32 + rsel)*512 + ksel*8;
  const f16 *gA0 = xhi + aoff,  *gA1 = gA0 + 16*512;
  const f16 *gAl0 = xlo + aoff, *gAl1 = gAl0 + 16*512;
  const f16 *gB0 = whi + boff,  *gB1 = gB0 + 16*512;
  f16 *lA0 = &Ah[2*w][0][0],  *lA1 = &Ah[2*w+1][0][0];
  f16 *lAl0 = &Al[2*w][0][0], *lAl1 = &Al[2*w+1][0][0];
  f16 *lB0 = &Bh[2*w][0][0],  *lB1 = &Bh[2*w+1][0][0];

  const f32x4 zero = {0.f, 0.f, 0.f, 0.f};
  f32x4 acc[4][4];
#pragma unroll
  for (int mt = 0; mt < 4; mt++)
#pragma unroll
    for (int nt = 0; nt < 4; nt++) acc[mt][nt] = zero;

  const int mb4 = (w & 1) * 4, nb4 = (w >> 1) * 4;
  for (int k0 = 0; k0 < 512; k0 += 32) {
    __syncthreads();
    gload_lds16(gA0 + k0, lA0);
    gload_lds16(gA1 + k0, lA1);
    gload_lds16(gB0 + k0, lB0);
    gload_lds16(gB1 + k0, lB1);
    if (SPLIT) {
      gload_lds16(gAl0 + k0, lAl0);
      gload_lds16(gAl1 + k0, lAl1);
    }
    __syncthreads();
    f16x8 bhf[4];
#pragma unroll
    for (int nt = 0; nt < 4; nt++) bhf[nt] = ((const f16x8*)&Bh[nb4+nt][0][0])[lane];
    if (SPLIT) {
#pragma unroll
      for (int mt = 0; mt < 4; mt++) {
        f16x8 ah = ((const f16x8*)&Ah[mb4+mt][0][0])[lane];
        f16x8 al = ((const f16x8*)&Al[mb4+mt][0][0])[lane];
#pragma unroll
        for (int nt = 0; nt < 4; nt++) {
          acc[mt][nt] = MFMA32(al, bhf[nt], acc[mt][nt]);
          acc[mt][nt] = MFMA32(ah, bhf[nt], acc[mt][nt]);
        }
      }
    } else {
#pragma unroll
      for (int mt = 0; mt < 4; mt++) {
        f16x8 ah = ((const f16x8*)&Ah[mb4+mt][0][0])[lane];
#pragma unroll
        for (int nt = 0; nt < 4; nt++)
          acc[mt][nt] = MFMA32(ah, bhf[nt], acc[mt][nt]);
      }
    }
  }

  const int mbase = m0 + (w & 1)*64, nbase = n0 + (w >> 1)*64;
  float bc[4];
#pragma unroll
  for (int nt = 0; nt < 4; nt++) bc[nt] = qkvb[nbase + nt*16 + rsel];
#pragma unroll
  for (int mt = 0; mt < 4; mt++)
#pragma unroll
    for (int nt = 0; nt < 4; nt++)
#pragma unroll
      for (int r = 0; r < 4; r++) acc[mt][nt][r] += bc[nt];

  if (by < 8) {   // Q or K: l2-normalize per head-row; single-f16 outputs
    const bool ISQ = (by < 4);
#pragma unroll
    for (int pair = 0; pair < 2; pair++) {
      const int h = ((nbase - (ISQ ? 0 : 512)) >> 5) + pair;
      float sc = 0.f, qe0 = 0.f, qe1 = 0.f;
      if (ISQ) {
        sc  = log1pf(__expf(temp[h])) * 10.0f;   // softplus * ln(1024) * log2(e)
        qe0 = qe[h*32 + rsel];
        qe1 = qe[h*32 + 16 + rsel];
      }
      f16* dh = ISQ ? qh_o : kh_o;
#pragma unroll
      for (int mt = 0; mt < 4; mt++) {
        float ss[4];
#pragma unroll
        for (int r = 0; r < 4; r++) {
          float a = acc[mt][2*pair][r], b = acc[mt][2*pair+1][r];
          ss[r] = a*a + b*b;
        }
        for (int s = 1; s < 16; s <<= 1) {
#pragma unroll
          for (int r = 0; r < 4; r++) ss[r] += __shfl_xor(ss[r], s, 64);
        }
#pragma unroll
        for (int r = 0; r < 4; r++) {
          float rn = 1.0f / fmaxf(sqrtf(ss[r]), 1e-12f);
          int m = mbase + mt*16 + ksel*4 + r;
          int b_ = m >> 10, p = m & 1023;
          size_t base = ((size_t)(b_*16 + h)*1024 + p)*32;
          float v0 = acc[mt][2*pair][r] * rn;
          float v1 = acc[mt][2*pair+1][r] * rn;
          if (ISQ) { v0 = (v0 + qe0) * sc; v1 = (v1 + qe1) * sc; }
          dh[base + rsel]      = (f16)v0;
          dh[base + 16 + rsel] = (f16)v1;
        }
      }
    }
  } else {        // V: write transposed [b][h][d][n]
#pragma unroll
    for (int mt = 0; mt < 4; mt++) {
      int m = mbase + mt*16 + ksel*4;
      int b_ = m >> 10, p = m & 1023;
#pragma unroll
      for (int nt = 0; nt < 4; nt++) {
        int n = nbase + nt*16 + rsel;
        int g = (n - 1024) >> 5, d = n & 31;
        f16x4 pk;
#pragma unroll
        for (int r = 0; r < 4; r++) pk[r] = (f16)acc[mt][nt][r];
        *(f16x4*)(vt_o + ((size_t)(b_*16 + g)*32 + d)*1024 + p) = pk;
      }
    }
  }
}

// ---------------- kernel 5: flash attention, two-phase max (no online softmax) -------------
// Phase A: QK MFMA + elementwise max only (no cross-lane, no exp). One 2-shuffle reduce.
// Phase B: recompute QK (bit-identical), p=exp2(S-mx)<=1, li+=p per-lane, PV MFMA.
// No per-iteration cross-lane ops and no O-rescale -> loop-carried deps are only the
// associative MFMA accumulates. Round-7 showed load latency is NOT the floor; the
// serial softmax chain was. K/bias read twice but XCD-L2-resident (round-6 swizzle).
__global__ __launch_bounds__(256, 4) void k_attn(
    const f16* __restrict__ qhi, const f16* __restrict__ khi, const f16* __restrict__ vt,
    const f16* __restrict__ bias_t,
    f16* __restrict__ po0, f16* __restrict__ po1,
    float2* __restrict__ ml0, float2* __restrict__ ml1)
{
  __shared__ __align__(16) f16 OT[4][32][40];
  const int lane = threadIdx.x & 63, w = threadIdx.x >> 6;
  const int rsel = lane & 15, ksel = lane >> 4;
  // decode swizzled block id: (xcd=h&7) | hHi | qt | split | b
  const int bid = blockIdx.x;
  const int xcd = bid & 7;
  const int r1 = bid >> 3;
  const int h = ((r1 & 1) << 3) | xcd;
  const int r2 = r1 >> 1;
  const int qt = r2 & 7, split = (r2 >> 3) & 1, b = r2 >> 4;
  const int bh = b*16 + h;
  const int q0 = qt*128 + w*32;
  const int mstart = split * 512;

  f16x8 Qh[2];
#pragma unroll
  for (int c = 0; c < 2; c++)
    Qh[c] = *(const f16x8*)(qhi + ((size_t)bh*1024 + q0 + c*16 + rsel)*32 + ksel*8);

  const char* kb = (const char*)(khi + (size_t)bh*32768);
  const char* vb = (const char*)(vt  + (size_t)bh*32768);
  const char* bbp = (const char*)(bias_t + (size_t)h*1048576);
  const int kOff0 = ((mstart + rsel)*32 + ksel*8) * 2;
  const int vOff0 = (rsel*1024 + mstart + ksel*4) * 2;
  const int bOff0 = (((mstart >> 2) + ksel)*1024 + q0 + rsel) * 8;

  // ---- phase A: per-lane max over own keys ----
  float mx[2] = {-3.0e38f, -3.0e38f};
  {
    int kOff = kOff0, bOff = bOff0;
    for (int it = 0; it < 16; ++it) {
      f16x8 K0 = *(const f16x8*)(kb + kOff);
      f16x8 K1 = *(const f16x8*)(kb + kOff + 1024);
      f16x4 Bb[2][2];
      Bb[0][0] = *(const f16x4*)(bbp + bOff);
      Bb[0][1] = *(const f16x4*)(bbp + bOff + 128);
      Bb[1][0] = *(const f16x4*)(bbp + bOff + 32768);
      Bb[1][1] = *(const f16x4*)(bbp + bOff + 32896);
      kOff += 2048; bOff += 65536;
#pragma unroll
      for (int f = 0; f < 2; f++)
#pragma unroll
        for (int c = 0; c < 2; c++) {
          f32x4 Ci;
#pragma unroll
          for (int r = 0; r < 4; r++) Ci[r] = (float)Bb[f][c][r];
          f32x4 St = MFMA32(f ? K1 : K0, Qh[c], Ci);
          mx[c] = fmaxf(mx[c], fmaxf(fmaxf(St[0], St[1]), fmaxf(St[2], St[3])));
        }
    }
  }
#pragma unroll
  for (int c = 0; c < 2; c++) {
    mx[c] = fmaxf(mx[c], __shfl_xor(mx[c], 16, 64));
    mx[c] = fmaxf(mx[c], __shfl_xor(mx[c], 32, 64));
  }

  // ---- phase B: exp + PV with fixed max ----
  f32x4 O[2][2];
  float li[2] = {0.f, 0.f};
  O[0][0] = (f32x4){0.f,0.f,0.f,0.f}; O[0][1] = O[0][0];
  O[1][0] = O[0][0]; O[1][1] = O[0][0];
  {
    int kOff = kOff0, vOff = vOff0, bOff = bOff0;
    for (int it = 0; it < 16; ++it) {
      f16x8 K0 = *(const f16x8*)(kb + kOff);
      f16x8 K1 = *(const f16x8*)(kb + kOff + 1024);
      f16x4 Va[2][2], Bb[2][2];
      Va[0][0] = *(const f16x4*)(vb + vOff);
      Va[1][0] = *(const f16x4*)(vb + vOff + 32);
      Va[0][1] = *(const f16x4*)(vb + vOff + 32768);
      Va[1][1] = *(const f16x4*)(vb + vOff + 32800);
      Bb[0][0] = *(const f16x4*)(bbp + bOff);
      Bb[0][1] = *(const f16x4*)(bbp + bOff + 128);
      Bb[1][0] = *(const f16x4*)(bbp + bOff + 32768);
      Bb[1][1] = *(const f16x4*)(bbp + bOff + 32896);
      kOff += 2048; vOff += 64; bOff += 65536;

      f16x4 P16[2][2];
#pragma unroll
      for (int f = 0; f < 2; f++)
#pragma unroll
        for (int c = 0; c < 2; c++) {
          f32x4 Ci;
#pragma unroll
          for (int r = 0; r < 4; r++) Ci[r] = (float)Bb[f][c][r];
          f32x4 St = MFMA32(f ? K1 : K0, Qh[c], Ci);
#pragma unroll
          for (int r = 0; r < 4; r++) {
            float p = fexp2(St[r] - mx[c]);
            li[c] += p;
            P16[f][c][r] = (f16)p;
          }
        }
#pragma unroll
      for (int c = 0; c < 2; c++)
#pragma unroll
        for (int dt = 0; dt < 2; dt++) {
          O[c][dt] = MFMA16(Va[0][dt], P16[0][c], O[c][dt]);
          O[c][dt] = MFMA16(Va[1][dt], P16[1][c], O[c][dt]);
        }
    }
  }

  // epilogue: reduce li across ksel groups, transpose O^T, write partial + (m,l)
#pragma unroll
  for (int c = 0; c < 2; c++) {
    li[c] += __shfl_xor(li[c], 16, 64);
    li[c] += __shfl_xor(li[c], 32, 64);
    float inv = 1.0f / li[c];
#pragma unroll
    for (int dt = 0; dt < 2; dt++)
#pragma unroll
      for (int r = 0; r < 4; r++)
        OT[w][c*16 + rsel][dt*16 + ksel*4 + r] = (f16)(O[c][dt][r] * inv);
  }
  f16* po_s = split ? po1 : po0;
  float2* ml_s = split ? ml1 : ml0;
  int row = lane >> 1, half = lane & 1;
  f16x8 o0 = *(const f16x8*)(&OT[w][row][half*16]);
  f16x8 o1 = *(const f16x8*)(&OT[w][row][half*16 + 8]);
  f16* outp = po_s + ((size_t)bh*1024 + q0 + row)*32 + half*16;
  *(f16x8*)outp = o0;
  *(f16x8*)(outp + 8) = o1;
  if (lane < 32) {
    int c = lane >> 4;
    float mm = c ? mx[1] : mx[0];
    float ll = c ? li[1] : li[0];
    ml_s[(size_t)bh*1024 + q0 + lane] = make_float2(mm, ll);
  }
}

// ---------------- kernel 5b: merge the two key-halves (base-2 m) ----------------
__global__ __launch_bounds__(256) void k_merge(
    const f16* __restrict__ po0, const f16* __restrict__ po1,
    const float2* __restrict__ ml0, const float2* __restrict__ ml1,
    f16* __restrict__ ao)
{
  int tid = blockIdx.x * 256 + threadIdx.x;
  int h = tid & 15, q = (tid >> 4) & 1023, b = tid >> 14;
  int bh = b*16 + h;
  size_t rec = (size_t)bh*1024 + q;
  float2 a = ml0[rec], c = ml1[rec];
  float M = fmaxf(a.x, c.x);
  float w0 = a.y * fexp2(a.x - M);
  float w1 = c.y * fexp2(c.x - M);
  float inv = 1.0f / (w0 + w1);
  w0 *= inv; w1 *= inv;
  const f16x8* p0 = (const f16x8*)(po0 + rec*32);
  const f16x8* p1 = (const f16x8*)(po1 + rec*32);
  f16* op = ao + ((size_t)b*1024 + q)*512 + h*32;
#pragma unroll
  for (int i = 0; i < 4; i++) {
    f16x8 x0 = p0[i], x1 = p1[i];
    f16x8 o;
#pragma unroll
    for (int j = 0; j < 8; j++) o[j] = (f16)((float)x0[j]*w0 + (float)x1[j]*w1);
    ((f16x8*)op)[i] = o;
  }
}

// ---------------- kernel 6: proj GEMM f16 -> fp32 out ----------------
__global__ __launch_bounds__(256) void k_proj(
    const f16* __restrict__ A, const f16* __restrict__ Bw,
    const float* __restrict__ pb, float* __restrict__ out)
{
  __shared__ __align__(16) f16 Ah[8][64][8];
  __shared__ __align__(16) f16 Bh[8][64][8];
  const int tid = threadIdx.x, lane = tid & 63, w = tid >> 6;
  const int rsel = lane & 15, ksel = lane >> 4;
  const int bx = blockIdx.x & 63, by = blockIdx.x >> 6;
  const int m0 = bx << 7, n0 = by << 7;
  const f16 *gA0 = A + (size_t)(m0 + w*32 + rsel)*512 + ksel*8,  *gA1 = gA0 + 16*512;
  const f16 *gB0 = Bw + (size_t)(n0 + w*32 + rsel)*512 + ksel*8, *gB1 = gB0 + 16*512;
  f16 *lA0 = &Ah[2*w][0][0], *lA1 = &Ah[2*w+1][0][0];
  f16 *lB0 = &Bh[2*w][0][0], *lB1 = &Bh[2*w+1][0][0];
  const f32x4 zero = {0.f, 0.f, 0.f, 0.f};
  f32x4 acc[4][4];
#pragma unroll
  for (int mt = 0; mt < 4; mt++)
#pragma unroll
    for (int nt = 0; nt < 4; nt++) acc[mt][nt] = zero;
  const int mb4 = (w & 1)*4, nb4 = (w >> 1)*4;
  for (int k0 = 0; k0 < 512; k0 += 32) {
    __syncthreads();
    gload_lds16(gA0 + k0, lA0);
    gload_lds16(gA1 + k0, lA1);
    gload_lds16(gB0 + k0, lB0);
    gload_lds16(gB1 + k0, lB1);
    __syncthreads();
    f16x8 bhf[4];
#pragma unroll
    for (int nt = 0; nt < 4; nt++) bhf[nt] = ((const f16x8*)&Bh[nb4+nt][0][0])[lane];
#pragma unroll
    for (int mt = 0; mt < 4; mt++) {
      f16x8 ah = ((const f16x8*)&Ah[mb4+mt][0][0])[lane];
#pragma unroll
      for (int nt = 0; nt < 4; nt++)
        acc[mt][nt] = MFMA32(ah, bhf[nt], acc[mt][nt]);
    }
  }
  const int mbase = m0 + (w & 1)*64, nbase = n0 + (w >> 1)*64;
  float bc[4];
#pragma unroll
  for (int nt = 0; nt < 4; nt++) bc[nt] = pb[nbase + nt*16 + rsel];
#pragma unroll
  for (int mt = 0; mt < 4; mt++)
#pragma unroll
    for (int nt = 0; nt < 4; nt++)
#pragma unroll
      for (int r = 0; r < 4; r++)
        out[(size_t)(mbase + mt*16 + ksel*4 + r)*512 + nbase + nt*16 + rsel] =
            acc[mt][nt][r] + bc[nt];
}

// ---------------- launch ----------------
extern "C" void kernel_launch(void* const* d_in, const int* in_sizes, int n_in,
                              void* d_out, int out_size, void* d_ws, size_t ws_size,
                              hipStream_t stream) {
  const float* x    = (const float*)d_in[0];
  const int*   rpi  = (const int*)d_in[3];
  const float* rct  = (const float*)d_in[4];
  const float* qw   = (const float*)d_in[5];
  const float* qb   = (const float*)d_in[6];
  const float* pwf  = (const float*)d_in[7];
  const float* pbv  = (const float*)d_in[8];
  const float* temp = (const float*)d_in[9];
  const float* qe   = (const float*)d_in[10];
  const float* f1w  = (const float*)d_in[11];
  const float* f1b  = (const float*)d_in[12];
  const float* f2w  = (const float*)d_in[13];
  const float* f2b  = (const float*)d_in[14];

  char* ws = (char*)d_ws;
  float* t_cpb  = (float*)(ws + OFF_TCPB);
  f16* bias_t   = (f16*)(ws + OFF_BIAS);
  f16* xhi = (f16*)(ws + OFF_XHI);
  f16* xlo = (f16*)(ws + OFF_XLO);
  f16* whi = (f16*)(ws + OFF_WHI);
  f16* pw  = (f16*)(ws + OFF_PW);
  f16* qhi = (f16*)(ws + OFF_QHI);
  f16* khi = (f16*)(ws + OFF_KHI);
  f16* vt  = (f16*)(ws + OFF_VT);
  f16* ao  = (f16*)(ws + OFF_AO);
  f16* po0 = (f16*)(ws + OFF_KLO);            // dead regions reused
  f16* po1 = (f16*)(ws + OFF_XHI);
  float2* ml0 = (float2*)(ws + OFF_XLO);
  float2* ml1 = ml0 + 131072;

  k_convert<<<5120, 256, 0, stream>>>(x, qw, pwf, xhi, xlo, whi, pw);
  k_cpb<<<993, 256, 0, stream>>>(rct, f1w, f1b, f2w, f2b, t_cpb);
  k_bias<<<1024, 256, 0, stream>>>(rpi, t_cpb, bias_t);
  k_qkv<<<768, 256, 0, stream>>>(xhi, xlo, whi, qb, temp, qe, qhi, khi, vt);
  k_attn<<<2048, 256, 0, stream>>>(qhi, khi, vt, bias_t, po0, po1, ml0, ml1);
  k_merge<<<512, 256, 0, stream>>>(po0, po1, ml0, ml1, ao);
  k_proj<<<256, 256, 0, stream>>>(ao, pw, pbv, (float*)d_out);
}

// Round 9
// 282.932 us; speedup vs baseline: 1.1198x; 1.1198x over previous
//
#include <hip/hip_runtime.h>
#include <cstdint>
#include <cstddef>

typedef _Float16 f16;
typedef _Float16 f16x4 __attribute__((ext_vector_type(4)));
typedef _Float16 f16x8 __attribute__((ext_vector_type(8)));
typedef float f32x4 __attribute__((ext_vector_type(4)));

#define MFMA32(a,b,c) __builtin_amdgcn_mfma_f32_16x16x32_f16((a),(b),(c),0,0,0)
#define MFMA16(a,b,c) __builtin_amdgcn_mfma_f32_16x16x16f16((a),(b),(c),0,0,0)

__device__ __forceinline__ float fexp2(float x) {
#if __has_builtin(__builtin_amdgcn_exp2f)
  return __builtin_amdgcn_exp2f(x);
#else
  return __expf(x * 0.69314718055994531f);
#endif
}

__device__ __forceinline__ void gload_lds16(const f16* g, f16* l) {
  __builtin_amdgcn_global_load_lds(
      (const __attribute__((address_space(1))) unsigned int*)g,
      (__attribute__((address_space(3))) unsigned int*)l, 16, 0, 0);
}

// ---------------- workspace layout (bytes) ----------------
static constexpr size_t OFF_TCPB = 0;                     // 3969*16*4 fp32 (base-2 domain)
static constexpr size_t OFF_BIAS = 262144;                // 16*1024*1024 f16  [h][m>>2][n][m&3]
static constexpr size_t OFF_XHI  = OFF_BIAS + 33554432;   // 8192*512 f16
static constexpr size_t OFF_XLO  = OFF_XHI + 8388608;
static constexpr size_t OFF_WHI  = OFF_XLO + 8388608;     // 1536*512 f16
static constexpr size_t OFF_WLO  = OFF_WHI + 1572864;     // (dead)
static constexpr size_t OFF_PW   = OFF_WLO + 1572864;     // 512*512 f16
static constexpr size_t OFF_QHI  = OFF_PW  + 524288;      // [B][H][N][32] f16 (pre-scaled q)
static constexpr size_t OFF_QLO  = OFF_QHI + 8388608;     // (dead)
static constexpr size_t OFF_KHI  = OFF_QLO + 8388608;
static constexpr size_t OFF_KLO  = OFF_KHI + 8388608;     // (dead)
static constexpr size_t OFF_VT   = OFF_KLO + 8388608;     // [B][H][32][N] f16
static constexpr size_t OFF_AO   = OFF_VT  + 8388608;     // [8192][512] f16

// ---------------- kernel 1: fp32 -> f16 (x gets hi+lo split; weights hi only) -------------
__global__ __launch_bounds__(256) void k_convert(
    const float* __restrict__ x, const float* __restrict__ qw, const float* __restrict__ pwf,
    f16* __restrict__ xhi, f16* __restrict__ xlo,
    f16* __restrict__ whi, f16* __restrict__ pw)
{
  int i = blockIdx.x * 256 + threadIdx.x;
  const float4* src; f16* dh; f16* dl; int j;
  if (i < 1048576)      { j = i;           src = (const float4*)x;   dh = xhi; dl = xlo; }
  else if (i < 1245184) { j = i - 1048576; src = (const float4*)qw;  dh = whi; dl = nullptr; }
  else                  { j = i - 1245184; src = (const float4*)pwf; dh = pw;  dl = nullptr; }
  float4 v = src[j];
  f16x4 h;
  h[0] = (f16)v.x; h[1] = (f16)v.y; h[2] = (f16)v.z; h[3] = (f16)v.w;
  ((f16x4*)dh)[j] = h;
  if (dl) {
    f16x4 l;
    l[0] = (f16)(v.x - (float)h[0]); l[1] = (f16)(v.y - (float)h[1]);
    l[2] = (f16)(v.z - (float)h[2]); l[3] = (f16)(v.w - (float)h[3]);
    ((f16x4*)dl)[j] = l;
  }
}

// ---------------- kernel 2: CPB MLP -> t[3969][16] fp32, scaled by log2e ----------------
__global__ __launch_bounds__(256) void k_cpb(
    const float* __restrict__ table, const float* __restrict__ w1, const float* __restrict__ b1,
    const float* __restrict__ w2, const float* __restrict__ b2, float* __restrict__ t_out)
{
  const int r = blockIdx.x * 4 + (threadIdx.x >> 6);
  const int lane = threadIdx.x & 63;
  if (r >= 3969) return;
  const float c0 = table[2*r], c1 = table[2*r+1];
  const int j0 = lane * 8;
  float h[8];
#pragma unroll
  for (int jj = 0; jj < 8; jj++) {
    int j = j0 + jj;
    float v = c0 * w1[2*j] + c1 * w1[2*j+1] + b1[j];
    h[jj] = v > 0.0f ? v : 0.0f;
  }
  float acc[16];
#pragma unroll
  for (int o = 0; o < 16; o++) {
    const float4* wp = (const float4*)(w2 + o*512 + j0);
    float4 a = wp[0], bb = wp[1];
    acc[o] = a.x*h[0] + a.y*h[1] + a.z*h[2] + a.w*h[3]
           + bb.x*h[4] + bb.y*h[5] + bb.z*h[6] + bb.w*h[7];
  }
#pragma unroll
  for (int o = 0; o < 16; o++) {
    float v = acc[o];
    for (int s = 1; s < 64; s <<= 1) v += __shfl_xor(v, s, 64);
    acc[o] = v;
  }
  if (lane == 0) {
#pragma unroll
    for (int o = 0; o < 16; o++)
      t_out[r*16 + o] = (acc[o] + b2[o]) * 1.4426950408889634f;
  }
}

// ---------------- kernel 3: bias gather, vectorized rows -> [h][m>>2][n][m&3] -------------
__global__ __launch_bounds__(256) void k_bias(
    const int* __restrict__ idx, const float* __restrict__ t_cpb, f16* __restrict__ bias_t)
{
  int g = blockIdx.x * 256 + threadIdx.x;   // 262144 = 256 m4 * 1024 n
  int n = g & 1023, m4 = g >> 10;
  int4 I = *(const int4*)(idx + (size_t)n*1024 + m4*4);
  int ids[4] = {I.x, I.y, I.z, I.w};
  const float4* T = (const float4*)t_cpb;
#pragma unroll
  for (int half = 0; half < 2; half++) {
    float4 R[4][2];
#pragma unroll
    for (int k = 0; k < 4; k++) {
      R[k][0] = T[ids[k]*4 + half*2];
      R[k][1] = T[ids[k]*4 + half*2 + 1];
    }
#pragma unroll
    for (int hh = 0; hh < 8; hh++) {
      int h = half*8 + hh;
      f16x4 o;
#pragma unroll
      for (int k = 0; k < 4; k++)
        o[k] = (f16)(((const float*)&R[k][hh >> 2])[hh & 3]);
      *(f16x4*)(bias_t + (((size_t)h*256 + m4)*1024 + n)*4) = o;
    }
  }
}

// ---------------- kernel 4: QKV GEMM (x split, w single-f16) + normalize epilogue ---------
__global__ __launch_bounds__(256) void k_qkv(
    const f16* __restrict__ xhi, const f16* __restrict__ xlo,
    const f16* __restrict__ whi,
    const float* __restrict__ qkvb, const float* __restrict__ temp, const float* __restrict__ qe,
    f16* __restrict__ qh_o, f16* __restrict__ kh_o, f16* __restrict__ vt_o)
{
  __shared__ __align__(16) f16 Ah[8][64][8];
  __shared__ __align__(16) f16 Al[8][64][8];
  __shared__ __align__(16) f16 Bh[8][64][8];
  const int tid = threadIdx.x, lane = tid & 63, w = tid >> 6;
  const int rsel = lane & 15, ksel = lane >> 4;
  const int bx = blockIdx.x & 63, by = blockIdx.x >> 6;
  const int m0 = bx << 7, n0 = by << 7;
  const bool SPLIT = (by < 8);

  const size_t aoff = (size_t)(m0 + w*32 + rsel)*512 + ksel*8;
  const size_t boff = (size_t)(n0 + w*32 + rsel)*512 + ksel*8;
  const f16 *gA0 = xhi + aoff,  *gA1 = gA0 + 16*512;
  const f16 *gAl0 = xlo + aoff, *gAl1 = gAl0 + 16*512;
  const f16 *gB0 = whi + boff,  *gB1 = gB0 + 16*512;
  f16 *lA0 = &Ah[2*w][0][0],  *lA1 = &Ah[2*w+1][0][0];
  f16 *lAl0 = &Al[2*w][0][0], *lAl1 = &Al[2*w+1][0][0];
  f16 *lB0 = &Bh[2*w][0][0],  *lB1 = &Bh[2*w+1][0][0];

  const f32x4 zero = {0.f, 0.f, 0.f, 0.f};
  f32x4 acc[4][4];
#pragma unroll
  for (int mt = 0; mt < 4; mt++)
#pragma unroll
    for (int nt = 0; nt < 4; nt++) acc[mt][nt] = zero;

  const int mb4 = (w & 1) * 4, nb4 = (w >> 1) * 4;
  for (int k0 = 0; k0 < 512; k0 += 32) {
    __syncthreads();
    gload_lds16(gA0 + k0, lA0);
    gload_lds16(gA1 + k0, lA1);
    gload_lds16(gB0 + k0, lB0);
    gload_lds16(gB1 + k0, lB1);
    if (SPLIT) {
      gload_lds16(gAl0 + k0, lAl0);
      gload_lds16(gAl1 + k0, lAl1);
    }
    __syncthreads();
    f16x8 bhf[4];
#pragma unroll
    for (int nt = 0; nt < 4; nt++) bhf[nt] = ((const f16x8*)&Bh[nb4+nt][0][0])[lane];
    if (SPLIT) {
#pragma unroll
      for (int mt = 0; mt < 4; mt++) {
        f16x8 ah = ((const f16x8*)&Ah[mb4+mt][0][0])[lane];
        f16x8 al = ((const f16x8*)&Al[mb4+mt][0][0])[lane];
#pragma unroll
        for (int nt = 0; nt < 4; nt++) {
          acc[mt][nt] = MFMA32(al, bhf[nt], acc[mt][nt]);
          acc[mt][nt] = MFMA32(ah, bhf[nt], acc[mt][nt]);
        }
      }
    } else {
#pragma unroll
      for (int mt = 0; mt < 4; mt++) {
        f16x8 ah = ((const f16x8*)&Ah[mb4+mt][0][0])[lane];
#pragma unroll
        for (int nt = 0; nt < 4; nt++)
          acc[mt][nt] = MFMA32(ah, bhf[nt], acc[mt][nt]);
      }
    }
  }

  const int mbase = m0 + (w & 1)*64, nbase = n0 + (w >> 1)*64;
  float bc[4];
#pragma unroll
  for (int nt = 0; nt < 4; nt++) bc[nt] = qkvb[nbase + nt*16 + rsel];
#pragma unroll
  for (int mt = 0; mt < 4; mt++)
#pragma unroll
    for (int nt = 0; nt < 4; nt++)
#pragma unroll
      for (int r = 0; r < 4; r++) acc[mt][nt][r] += bc[nt];

  if (by < 8) {   // Q or K: l2-normalize per head-row; single-f16 outputs
    const bool ISQ = (by < 4);
#pragma unroll
    for (int pair = 0; pair < 2; pair++) {
      const int h = ((nbase - (ISQ ? 0 : 512)) >> 5) + pair;
      float sc = 0.f, qe0 = 0.f, qe1 = 0.f;
      if (ISQ) {
        sc  = log1pf(__expf(temp[h])) * 10.0f;   // softplus * ln(1024) * log2(e)
        qe0 = qe[h*32 + rsel];
        qe1 = qe[h*32 + 16 + rsel];
      }
      f16* dh = ISQ ? qh_o : kh_o;
#pragma unroll
      for (int mt = 0; mt < 4; mt++) {
        float ss[4];
#pragma unroll
        for (int r = 0; r < 4; r++) {
          float a = acc[mt][2*pair][r], b = acc[mt][2*pair+1][r];
          ss[r] = a*a + b*b;
        }
        for (int s = 1; s < 16; s <<= 1) {
#pragma unroll
          for (int r = 0; r < 4; r++) ss[r] += __shfl_xor(ss[r], s, 64);
        }
#pragma unroll
        for (int r = 0; r < 4; r++) {
          float rn = 1.0f / fmaxf(sqrtf(ss[r]), 1e-12f);
          int m = mbase + mt*16 + ksel*4 + r;
          int b_ = m >> 10, p = m & 1023;
          size_t base = ((size_t)(b_*16 + h)*1024 + p)*32;
          float v0 = acc[mt][2*pair][r] * rn;
          float v1 = acc[mt][2*pair+1][r] * rn;
          if (ISQ) { v0 = (v0 + qe0) * sc; v1 = (v1 + qe1) * sc; }
          dh[base + rsel]      = (f16)v0;
          dh[base + 16 + rsel] = (f16)v1;
        }
      }
    }
  } else {        // V: write transposed [b][h][d][n]
#pragma unroll
    for (int mt = 0; mt < 4; mt++) {
      int m = mbase + mt*16 + ksel*4;
      int b_ = m >> 10, p = m & 1023;
#pragma unroll
      for (int nt = 0; nt < 4; nt++) {
        int n = nbase + nt*16 + rsel;
        int g = (n - 1024) >> 5, d = n & 31;
        f16x4 pk;
#pragma unroll
        for (int r = 0; r < 4; r++) pk[r] = (f16)acc[mt][nt][r];
        *(f16x4*)(vt_o + ((size_t)(b_*16 + g)*32 + d)*1024 + p) = pk;
      }
    }
  }
}

// ---------------- kernel 5: flash attention, intra-block split-K=4, LDS merge -------------
// r7 online-softmax body (best known: 97us) + (a) 4 waves share one (b,h,q-tile), each
// owning a 256-key quarter -> 8 chunks/wave, merge in LDS, write ao directly (k_merge and
// its po/ml HBM round-trip deleted); (b) wave-uniform alpha==1 fast path skips O-rescale.
__global__ __launch_bounds__(256, 4) void k_attn(
    const f16* __restrict__ qhi, const f16* __restrict__ khi, const f16* __restrict__ vt,
    const f16* __restrict__ bias_t, f16* __restrict__ ao)
{
  __shared__ __align__(16) f16 OT[4][32][36];     // per-wave normalized O^T partials
  __shared__ __align__(16) float2 ML[4][32];      // per-wave (m, l) per q-row
  const int lane = threadIdx.x & 63, w = threadIdx.x >> 6;
  const int rsel = lane & 15, ksel = lane >> 4;
  // decode swizzled block id: (xcd=h&7) | qt(5) | hHi(1) | b(3)  -> 4096 blocks
  const int bid = blockIdx.x;
  const int xcd = bid & 7;
  const int r1 = bid >> 3;
  const int qt = r1 & 31;
  const int r2 = r1 >> 5;
  const int hHi = r2 & 1, b = r2 >> 1;
  const int h = (hHi << 3) | xcd;
  const int bh = b*16 + h;
  const int q0 = qt*32;
  const int mstart = w*256;

  f16x8 Qh[2];
#pragma unroll
  for (int c = 0; c < 2; c++)
    Qh[c] = *(const f16x8*)(qhi + ((size_t)bh*1024 + q0 + c*16 + rsel)*32 + ksel*8);

  const char* kb = (const char*)(khi + (size_t)bh*32768);
  const char* vb = (const char*)(vt  + (size_t)bh*32768);
  const char* bbp = (const char*)(bias_t + (size_t)h*1048576);
  int kOff = ((mstart + rsel)*32 + ksel*8) * 2;
  int vOff = (rsel*1024 + mstart + ksel*4) * 2;
  int bOff = (((mstart >> 2) + ksel)*1024 + q0 + rsel) * 8;

  f32x4 O[2][2];
  float mi[2], li[2];
#pragma unroll
  for (int c = 0; c < 2; c++) {
    O[c][0] = (f32x4){0.f,0.f,0.f,0.f};
    O[c][1] = (f32x4){0.f,0.f,0.f,0.f};
    mi[c] = -3.0e38f; li[c] = 0.f;
  }

  for (int it = 0; it < 8; ++it) {
    f16x8 K0 = *(const f16x8*)(kb + kOff);
    f16x8 K1 = *(const f16x8*)(kb + kOff + 1024);
    f16x4 Va[2][2], Bb[2][2];
    Va[0][0] = *(const f16x4*)(vb + vOff);
    Va[1][0] = *(const f16x4*)(vb + vOff + 32);
    Va[0][1] = *(const f16x4*)(vb + vOff + 32768);
    Va[1][1] = *(const f16x4*)(vb + vOff + 32800);
    Bb[0][0] = *(const f16x4*)(bbp + bOff);
    Bb[0][1] = *(const f16x4*)(bbp + bOff + 128);
    Bb[1][0] = *(const f16x4*)(bbp + bOff + 32768);
    Bb[1][1] = *(const f16x4*)(bbp + bOff + 32896);
    kOff += 2048; vOff += 64; bOff += 65536;

    f32x4 St[2][2];
#pragma unroll
    for (int f = 0; f < 2; f++)
#pragma unroll
      for (int c = 0; c < 2; c++) {
        f32x4 Ci;
#pragma unroll
        for (int r = 0; r < 4; r++) Ci[r] = (float)Bb[f][c][r];
        St[f][c] = MFMA32(f ? K1 : K0, Qh[c], Ci);
      }

    f16x4 P16[2][2];
#pragma unroll
    for (int c = 0; c < 2; c++) {
      float cm = fmaxf(fmaxf(fmaxf(St[0][c][0], St[0][c][1]), fmaxf(St[0][c][2], St[0][c][3])),
                       fmaxf(fmaxf(St[1][c][0], St[1][c][1]), fmaxf(St[1][c][2], St[1][c][3])));
      cm = fmaxf(cm, __shfl_xor(cm, 16, 64));
      cm = fmaxf(cm, __shfl_xor(cm, 32, 64));
      bool upd = cm > mi[c];
      float mn = upd ? cm : mi[c];
      float rs = 0.f;
#pragma unroll
      for (int f = 0; f < 2; f++)
#pragma unroll
        for (int r = 0; r < 4; r++) {
          float p = fexp2(St[f][c][r] - mn);
          rs += p;
          P16[f][c][r] = (f16)p;
        }
      if (__ballot(upd)) {            // wave-uniform: any row's max advanced
        float alpha = fexp2(mi[c] - mn);
        mi[c] = mn;
        li[c] = li[c]*alpha + rs;
#pragma unroll
        for (int dt = 0; dt < 2; dt++)
#pragma unroll
          for (int r = 0; r < 4; r++) O[c][dt][r] *= alpha;
      } else {
        li[c] += rs;
      }
    }
#pragma unroll
    for (int c = 0; c < 2; c++)
#pragma unroll
      for (int dt = 0; dt < 2; dt++) {
        O[c][dt] = MFMA16(Va[0][dt], P16[0][c], O[c][dt]);
        O[c][dt] = MFMA16(Va[1][dt], P16[1][c], O[c][dt]);
      }
  }

  // per-wave epilogue: reduce li across ksel, store normalized partial + (m,l) in LDS
#pragma unroll
  for (int c = 0; c < 2; c++) {
    li[c] += __shfl_xor(li[c], 16, 64);
    li[c] += __shfl_xor(li[c], 32, 64);
    float inv = 1.0f / li[c];
#pragma unroll
    for (int dt = 0; dt < 2; dt++)
#pragma unroll
      for (int r = 0; r < 4; r++)
        OT[w][c*16 + rsel][dt*16 + ksel*4 + r] = (f16)(O[c][dt][r] * inv);
    if (ksel == 0) ML[w][c*16 + rsel] = make_float2(mi[c], li[c]);
  }
  __syncthreads();

  // block epilogue: 4-way softmax-consistent merge, write ao directly
  {
    int t = threadIdx.x;
    int q = t >> 3, dg = t & 7;          // q row 0..31, d group 0..7 (4 d each)
    float2 m0_ = ML[0][q], m1_ = ML[1][q], m2_ = ML[2][q], m3_ = ML[3][q];
    float M = fmaxf(fmaxf(m0_.x, m1_.x), fmaxf(m2_.x, m3_.x));
    float w0 = m0_.y * fexp2(m0_.x - M);
    float w1 = m1_.y * fexp2(m1_.x - M);
    float w2 = m2_.y * fexp2(m2_.x - M);
    float w3 = m3_.y * fexp2(m3_.x - M);
    float inv = 1.0f / (w0 + w1 + w2 + w3);
    f16x4 p0 = *(const f16x4*)(&OT[0][q][dg*4]);
    f16x4 p1 = *(const f16x4*)(&OT[1][q][dg*4]);
    f16x4 p2 = *(const f16x4*)(&OT[2][q][dg*4]);
    f16x4 p3 = *(const f16x4*)(&OT[3][q][dg*4]);
    f16x4 o;
#pragma unroll
    for (int r = 0; r < 4; r++)
      o[r] = (f16)(((float)p0[r]*w0 + (float)p1[r]*w1 + (float)p2[r]*w2 + (float)p3[r]*w3) * inv);
    *(f16x4*)(ao + ((size_t)b*1024 + q0 + q)*512 + h*32 + dg*4) = o;
  }
}

// ---------------- kernel 6: proj GEMM f16 -> fp32 out ----------------
__global__ __launch_bounds__(256) void k_proj(
    const f16* __restrict__ A, const f16* __restrict__ Bw,
    const float* __restrict__ pb, float* __restrict__ out)
{
  __shared__ __align__(16) f16 Ah[8][64][8];
  __shared__ __align__(16) f16 Bh[8][64][8];
  const int tid = threadIdx.x, lane = tid & 63, w = tid >> 6;
  const int rsel = lane & 15, ksel = lane >> 4;
  const int bx = blockIdx.x & 63, by = blockIdx.x >> 6;
  const int m0 = bx << 7, n0 = by << 7;
  const f16 *gA0 = A + (size_t)(m0 + w*32 + rsel)*512 + ksel*8,  *gA1 = gA0 + 16*512;
  const f16 *gB0 = Bw + (size_t)(n0 + w*32 + rsel)*512 + ksel*8, *gB1 = gB0 + 16*512;
  f16 *lA0 = &Ah[2*w][0][0], *lA1 = &Ah[2*w+1][0][0];
  f16 *lB0 = &Bh[2*w][0][0], *lB1 = &Bh[2*w+1][0][0];
  const f32x4 zero = {0.f, 0.f, 0.f, 0.f};
  f32x4 acc[4][4];
#pragma unroll
  for (int mt = 0; mt < 4; mt++)
#pragma unroll
    for (int nt = 0; nt < 4; nt++) acc[mt][nt] = zero;
  const int mb4 = (w & 1)*4, nb4 = (w >> 1)*4;
  for (int k0 = 0; k0 < 512; k0 += 32) {
    __syncthreads();
    gload_lds16(gA0 + k0, lA0);
    gload_lds16(gA1 + k0, lA1);
    gload_lds16(gB0 + k0, lB0);
    gload_lds16(gB1 + k0, lB1);
    __syncthreads();
    f16x8 bhf[4];
#pragma unroll
    for (int nt = 0; nt < 4; nt++) bhf[nt] = ((const f16x8*)&Bh[nb4+nt][0][0])[lane];
#pragma unroll
    for (int mt = 0; mt < 4; mt++) {
      f16x8 ah = ((const f16x8*)&Ah[mb4+mt][0][0])[lane];
#pragma unroll
      for (int nt = 0; nt < 4; nt++)
        acc[mt][nt] = MFMA32(ah, bhf[nt], acc[mt][nt]);
    }
  }
  const int mbase = m0 + (w & 1)*64, nbase = n0 + (w >> 1)*64;
  float bc[4];
#pragma unroll
  for (int nt = 0; nt < 4; nt++) bc[nt] = pb[nbase + nt*16 + rsel];
#pragma unroll
  for (int mt = 0; mt < 4; mt++)
#pragma unroll
    for (int nt = 0; nt < 4; nt++)
#pragma unroll
      for (int r = 0; r < 4; r++)
        out[(size_t)(mbase + mt*16 + ksel*4 + r)*512 + nbase + nt*16 + rsel] =
            acc[mt][nt][r] + bc[nt];
}

// ---------------- launch ----------------
extern "C" void kernel_launch(void* const* d_in, const int* in_sizes, int n_in,
                              void* d_out, int out_size, void* d_ws, size_t ws_size,
                              hipStream_t stream) {
  const float* x    = (const float*)d_in[0];
  const int*   rpi  = (const int*)d_in[3];
  const float* rct  = (const float*)d_in[4];
  const float* qw   = (const float*)d_in[5];
  const float* qb   = (const float*)d_in[6];
  const float* pwf  = (const float*)d_in[7];
  const float* pbv  = (const float*)d_in[8];
  const float* temp = (const float*)d_in[9];
  const float* qe   = (const float*)d_in[10];
  const float* f1w  = (const float*)d_in[11];
  const float* f1b  = (const float*)d_in[12];
  const float* f2w  = (const float*)d_in[13];
  const float* f2b  = (const float*)d_in[14];

  char* ws = (char*)d_ws;
  float* t_cpb  = (float*)(ws + OFF_TCPB);
  f16* bias_t   = (f16*)(ws + OFF_BIAS);
  f16* xhi = (f16*)(ws + OFF_XHI);
  f16* xlo = (f16*)(ws + OFF_XLO);
  f16* whi = (f16*)(ws + OFF_WHI);
  f16* pw  = (f16*)(ws + OFF_PW);
  f16* qhi = (f16*)(ws + OFF_QHI);
  f16* khi = (f16*)(ws + OFF_KHI);
  f16* vt  = (f16*)(ws + OFF_VT);
  f16* ao  = (f16*)(ws + OFF_AO);

  k_convert<<<5120, 256, 0, stream>>>(x, qw, pwf, xhi, xlo, whi, pw);
  k_cpb<<<993, 256, 0, stream>>>(rct, f1w, f1b, f2w, f2b, t_cpb);
  k_bias<<<1024, 256, 0, stream>>>(rpi, t_cpb, bias_t);
  k_qkv<<<768, 256, 0, stream>>>(xhi, xlo, whi, qb, temp, qe, qhi, khi, vt);
  k_attn<<<4096, 256, 0, stream>>>(qhi, khi, vt, bias_t, ao);
  k_proj<<<256, 256, 0, stream>>>(ao, pw, pbv, (float*)d_out);
}